// Round 12
// baseline (700.942 us; speedup 1.0000x reference)
//
#include <hip/hip_runtime.h>
#include <cstdint>
#include <cstddef>

#define NPTS 500000

using f16   = _Float16;
using f16x4 = __attribute__((ext_vector_type(4))) _Float16;
using f16x8 = __attribute__((ext_vector_type(8))) _Float16;
using f32x4 = __attribute__((ext_vector_type(4))) float;
using f32x16= __attribute__((ext_vector_type(16))) float;

// ---- ws layout (bytes). f16 weight images, pre-transposed W^T[m][k], output rows
// phi-permuted (phi = swap bits 2<->3; double-phi cancels so image k = global k).
// in/skip split into two 32KB halves (groups 0-3 / 4-7, sin/cos K-interleaved).
// Bias image stored f16 (first 5634B of the WS_BIAS region).
#define WS_INW   0u           // 2 x 32768
#define WS_SKIP  65536u       // 4 x 65536
#define WS_W1    327680u      // 8 x 32768  [128m][128k] f16, pitch 256B
#define WS_W2    589824u      // 8 x 32768  [128m][128k] f16
#define WS_BIAS  851968u      // 22*128 f16: arr[M][pos] = b_M[phi(pos)]
#define WS_BC    863232u      // 256 f32: B coeffs prescaled by 1/(2pi)
#define WS_OB    864256u      // 1 f32 + pad
#define WS_TOTAL 864272u

__device__ __host__ __forceinline__ int phi(int m) {
  return (m & ~12) | ((m & 4) << 1) | ((m & 8) >> 1);
}

// ---------------- prep: pack everything into ws
extern "C" __global__ void pinn_prep(const float* __restrict__ in_w,
                                     const float* __restrict__ w1,
                                     const float* __restrict__ w2,
                                     const float* __restrict__ skw,
                                     const float* __restrict__ inb,
                                     const float* __restrict__ b1,
                                     const float* __restrict__ b2,
                                     const float* __restrict__ skb,
                                     const float* __restrict__ ow,
                                     const float* __restrict__ ob,
                                     const float* __restrict__ Bg,
                                     char* __restrict__ ws) {
  int idx = (int)blockIdx.x * 256 + (int)threadIdx.x;
  if (idx < 32768) {                       // in_w halves [2][128m][128c]
    int H = idx >> 14, r = idx & 16383, m = r >> 7, c = r & 127;
    int gl = c >> 5, sc = (c >> 4) & 1, lo = c & 15;
    int k = sc * 128 + (H * 4 + gl) * 16 + lo;
    uint32_t off = (uint32_t)(m * 256 + c * 2) ^ (uint32_t)((m & 15) << 4);
    *(f16*)(ws + WS_INW + (uint32_t)H * 32768u + off) = (f16)in_w[k * 128 + phi(m)];
  } else if (idx < 163840) {               // skip halves [4][2][128][128]
    int r0 = idx - 32768;
    int j4 = r0 >> 15, rr = r0 & 32767;
    int H = rr >> 14, r = rr & 16383, m = r >> 7, c = r & 127;
    int gl = c >> 5, sc = (c >> 4) & 1, lo = c & 15;
    int k = sc * 128 + (H * 4 + gl) * 16 + lo;
    uint32_t off = (uint32_t)(m * 256 + c * 2) ^ (uint32_t)((m & 15) << 4);
    *(f16*)(ws + WS_SKIP + (uint32_t)j4 * 65536u + (uint32_t)H * 32768u + off) =
        (f16)skw[(j4 * 256 + k) * 128 + phi(m)];
  } else if (idx < 294912) {               // w1 [8][128m][128k]
    int r0 = idx - 163840;
    int i = r0 >> 14, r = r0 & 16383, m = r >> 7, k = r & 127;
    uint32_t off = (uint32_t)(m * 256 + k * 2) ^ (uint32_t)((m & 15) << 4);
    *(f16*)(ws + WS_W1 + (uint32_t)i * 32768u + off) = (f16)w1[(i * 128 + k) * 128 + phi(m)];
  } else if (idx < 425984) {               // w2 [8][128m][128k] f16
    int r0 = idx - 294912;
    int i = r0 >> 14, r = r0 & 16383, m = r >> 7, k = r & 127;
    uint32_t off = (uint32_t)(m * 256 + k * 2) ^ (uint32_t)((m & 15) << 4);
    *(f16*)(ws + WS_W2 + (uint32_t)i * 32768u + off) = (f16)w2[(i * 128 + k) * 128 + phi(m)];
  } else if (idx < 428800) {               // bias image (f16)
    int r = idx - 425984;
    int M = r >> 7, pos = r & 127;
    int pp = phi(pos);
    float v;
    if (M == 0)        v = inb[pp];
    else if (M <= 16)  { int t = M - 1; int i = t >> 1; v = (t & 1) ? b2[i * 128 + pp] : b1[i * 128 + pp]; }
    else if (M <= 20)  v = skb[(M - 17) * 128 + pp];
    else               v = ow[pp];
    *(f16*)(ws + WS_BIAS + (uint32_t)r * 2u) = (f16)v;
  } else if (idx < 429056) {               // Bc coeffs: slot (g,hi): row0 j..j+8, row1 j..j+8
    int r = idx - 428800;
    int slot = r >> 4, e2 = r & 15;
    int kq = slot >> 1, hb = slot & 1;
    int row = e2 >> 3, e = e2 & 7;
    int j = kq * 16 + hb * 8 + e;
    *(float*)(ws + WS_BC + (uint32_t)r * 4u) = Bg[row * 128 + j] * 0.15915494309189535f;
  } else if (idx == 429056) {
    *(float*)(ws + WS_OB) = ob[0];
    *(float*)(ws + WS_OB + 4) = 0.f; *(float*)(ws + WS_OB + 8) = 0.f; *(float*)(ws + WS_OB + 12) = 0.f;
  }
}

// ---------------- device math
__device__ __forceinline__ float ftanh(float x) {
  float e = __builtin_amdgcn_exp2f(x * 2.8853901817f);
  return 1.0f - 2.0f * __builtin_amdgcn_rcpf(e + 1.0f);
}
__device__ __forceinline__ float fsin_rev(float rev) {
  return __builtin_amdgcn_sinf(__builtin_amdgcn_fractf(rev));
}

// async global->LDS, 16B per lane; 4 waves cover 32KB (wave wv: 8KB at wv*8192)
__device__ __forceinline__ void gll16(const char* g, char* l) {
  __builtin_amdgcn_global_load_lds((const __attribute__((address_space(1))) void*)g,
                                   (__attribute__((address_space(3))) void*)l, 16, 0, 0);
}
__device__ __forceinline__ void stage32(const char* g, char* l, int wv, int ln64) {
  const char* gs = g + wv * 8192 + ln64 * 16;
  char* ls = l + wv * 8192;
  #pragma unroll
  for (int it = 0; it < 8; ++it) gll16(gs + it * 1024, ls + it * 1024);
}

#define MFMA_(a,b,c)  __builtin_amdgcn_mfma_f32_32x32x16_f16(a,b,c,0,0,0)

// f16 image fragment load: pitch 256B, XOR mask 15
#define LDW(BASE, MT, KB) (*(const f16x8*)((BASE) + \
  ((((uint32_t)(MT)*32u + lnr)*256u + (uint32_t)(KB)*32u + hi16v) ^ SW16)))

// bias acc init from f16 LDS image (broadcast reads within hi-half)
#define BINIT(acc, Mi, MT) { const f16* _bp = biasH + ((Mi)*128 + (MT)*32 + hi4); \
  f16x4 _q0 = *(const f16x4*)_bp;        f16x4 _q1 = *(const f16x4*)(_bp+8); \
  f16x4 _q2 = *(const f16x4*)(_bp+16);   f16x4 _q3 = *(const f16x4*)(_bp+24); \
  acc[0]=(float)_q0[0]; acc[1]=(float)_q0[1]; acc[2]=(float)_q0[2]; acc[3]=(float)_q0[3]; \
  acc[4]=(float)_q1[0]; acc[5]=(float)_q1[1]; acc[6]=(float)_q1[2]; acc[7]=(float)_q1[3]; \
  acc[8]=(float)_q2[0]; acc[9]=(float)_q2[1]; acc[10]=(float)_q2[2]; acc[11]=(float)_q2[3]; \
  acc[12]=(float)_q3[0]; acc[13]=(float)_q3[1]; acc[14]=(float)_q3[2]; acc[15]=(float)_q3[3]; }

#define UNPADD(acc, F0, F1) { \
  acc[0]+=(float)F0[0]; acc[1]+=(float)F0[1]; acc[2]+=(float)F0[2]; acc[3]+=(float)F0[3]; \
  acc[4]+=(float)F0[4]; acc[5]+=(float)F0[5]; acc[6]+=(float)F0[6]; acc[7]+=(float)F0[7]; \
  acc[8]+=(float)F1[0]; acc[9]+=(float)F1[1]; acc[10]+=(float)F1[2]; acc[11]+=(float)F1[3]; \
  acc[12]+=(float)F1[4]; acc[13]+=(float)F1[5]; acc[14]+=(float)F1[6]; acc[15]+=(float)F1[7]; }

#define FPACK(F0, F1, acc) { f16x8 _g0, _g1; \
  _g0[0]=(f16)acc[0]; _g0[1]=(f16)acc[1]; _g0[2]=(f16)acc[2]; _g0[3]=(f16)acc[3]; \
  _g0[4]=(f16)acc[4]; _g0[5]=(f16)acc[5]; _g0[6]=(f16)acc[6]; _g0[7]=(f16)acc[7]; \
  _g1[0]=(f16)acc[8]; _g1[1]=(f16)acc[9]; _g1[2]=(f16)acc[10]; _g1[3]=(f16)acc[11]; \
  _g1[4]=(f16)acc[12]; _g1[5]=(f16)acc[13]; _g1[6]=(f16)acc[14]; _g1[7]=(f16)acc[15]; \
  F0=_g0; F1=_g1; }

#define TPACK(F0, F1, acc) { f16x8 _g0, _g1; \
  _g0[0]=(f16)ftanh(acc[0]); _g0[1]=(f16)ftanh(acc[1]); _g0[2]=(f16)ftanh(acc[2]); _g0[3]=(f16)ftanh(acc[3]); \
  _g0[4]=(f16)ftanh(acc[4]); _g0[5]=(f16)ftanh(acc[5]); _g0[6]=(f16)ftanh(acc[6]); _g0[7]=(f16)ftanh(acc[7]); \
  _g1[0]=(f16)ftanh(acc[8]); _g1[1]=(f16)ftanh(acc[9]); _g1[2]=(f16)ftanh(acc[10]); _g1[3]=(f16)ftanh(acc[11]); \
  _g1[4]=(f16)ftanh(acc[12]); _g1[5]=(f16)ftanh(acc[13]); _g1[6]=(f16)ftanh(acc[14]); _g1[7]=(f16)ftanh(acc[15]); \
  F0=_g0; F1=_g1; }

#define OM2PI 4.7746482927f
#define SINPACK(F0, F1, acc) { f16x8 _g0, _g1; \
  _g0[0]=(f16)fsin_rev(acc[0]*OM2PI); _g0[1]=(f16)fsin_rev(acc[1]*OM2PI); \
  _g0[2]=(f16)fsin_rev(acc[2]*OM2PI); _g0[3]=(f16)fsin_rev(acc[3]*OM2PI); \
  _g0[4]=(f16)fsin_rev(acc[4]*OM2PI); _g0[5]=(f16)fsin_rev(acc[5]*OM2PI); \
  _g0[6]=(f16)fsin_rev(acc[6]*OM2PI); _g0[7]=(f16)fsin_rev(acc[7]*OM2PI); \
  _g1[0]=(f16)fsin_rev(acc[8]*OM2PI); _g1[1]=(f16)fsin_rev(acc[9]*OM2PI); \
  _g1[2]=(f16)fsin_rev(acc[10]*OM2PI); _g1[3]=(f16)fsin_rev(acc[11]*OM2PI); \
  _g1[4]=(f16)fsin_rev(acc[12]*OM2PI); _g1[5]=(f16)fsin_rev(acc[13]*OM2PI); \
  _g1[6]=(f16)fsin_rev(acc[14]*OM2PI); _g1[7]=(f16)fsin_rev(acc[15]*OM2PI); \
  F0=_g0; F1=_g1; }

// trig for feature slot ei of this lane's ONE point (sv,tv)
#define FFE(ei, CA, CB) { \
  float _r = __builtin_amdgcn_fractf(sv*(CA) + tv*(CB)); \
  _s[ei] = (f16)__builtin_amdgcn_sinf(_r); _c[ei] = (f16)__builtin_amdgcn_cosf(_r); }
#define FF2(G, FS, FC) { const float* _cp = BcL + ((G)*2 + hi)*16; \
  f32x4 _a0 = *(const f32x4*)_cp, _a1 = *(const f32x4*)(_cp+4); \
  f32x4 _b0 = *(const f32x4*)(_cp+8), _b1 = *(const f32x4*)(_cp+12); \
  f16x8 _s, _c; \
  FFE(0,_a0[0],_b0[0]) FFE(1,_a0[1],_b0[1]) FFE(2,_a0[2],_b0[2]) FFE(3,_a0[3],_b0[3]) \
  FFE(4,_a1[0],_b1[0]) FFE(5,_a1[1],_b1[1]) FFE(6,_a1[2],_b1[2]) FFE(7,_a1[3],_b1[3]) \
  FS = _s; FC = _c; }

// one Fourier group into all 4 mtile accs (trig computed ONCE per layer per g)
#define FFG(G) { f16x8 _fs,_fc; FF2(G,_fs,_fc) \
  { f16x8 _w=LDW(sS_,0,((G)&3)*2);   a0=MFMA_(_w,_fs,a0); } \
  { f16x8 _w=LDW(sS_,0,((G)&3)*2+1); a0=MFMA_(_w,_fc,a0); } \
  { f16x8 _w=LDW(sS_,1,((G)&3)*2);   a1=MFMA_(_w,_fs,a1); } \
  { f16x8 _w=LDW(sS_,1,((G)&3)*2+1); a1=MFMA_(_w,_fc,a1); } \
  { f16x8 _w=LDW(sS_,2,((G)&3)*2);   a2=MFMA_(_w,_fs,a2); } \
  { f16x8 _w=LDW(sS_,2,((G)&3)*2+1); a2=MFMA_(_w,_fc,a2); } \
  { f16x8 _w=LDW(sS_,3,((G)&3)*2);   a3=MFMA_(_w,_fs,a3); } \
  { f16x8 _w=LDW(sS_,3,((G)&3)*2+1); a3=MFMA_(_w,_fc,a3); } }

#define W1K(kb) { f16x8 _a = LDW(sS_, MTv, kb); acc = MFMA_(_a, x##kb, acc); }
#define W1TILE(MT, U0, U1) { const uint32_t MTv = (MT); \
  f32x16 acc; BINIT(acc, Mw1, MT) \
  W1K(0) W1K(1) W1K(2) W1K(3) W1K(4) W1K(5) W1K(6) W1K(7) \
  TPACK(U0, U1, acc) }

#define W2K(kb) { f16x8 _a = LDW(sS_, MTv, kb); acc = MFMA_(_a, u##kb, acc); }
#define W2TILE(MT, X0, X1) { const uint32_t MTv = (MT); \
  f32x16 acc; BINIT(acc, Mw2, MT) \
  W2K(0) W2K(1) W2K(2) W2K(3) W2K(4) W2K(5) W2K(6) W2K(7) \
  f16x8 _t0,_t1; FPACK(_t0,_t1,acc) X0 = X0 + _t0; X1 = X1 + _t1; }   // v_pk_add_f16

#define OWDOT(P, F0, F1, bp) P += (float)F0[0]*(float)bp[0] + (float)F0[1]*(float)bp[1] \
  + (float)F0[2]*(float)bp[2]  + (float)F0[3]*(float)bp[3] \
  + (float)F0[4]*(float)bp[8]  + (float)F0[5]*(float)bp[9] \
  + (float)F0[6]*(float)bp[10] + (float)F0[7]*(float)bp[11] \
  + (float)F1[0]*(float)bp[16] + (float)F1[1]*(float)bp[17] \
  + (float)F1[2]*(float)bp[18] + (float)F1[3]*(float)bp[19] \
  + (float)F1[4]*(float)bp[24] + (float)F1[5]*(float)bp[25] \
  + (float)F1[6]*(float)bp[26] + (float)F1[7]*(float)bp[27];

// ---------------- main: 256 thr = 4 waves x 32 pts = 128 pts/block; 4 blocks/CU.
// Measured launch-bounds model (R8/R10/R11): arg2 caps residency at arg2 waves/EU
// and VGPR cap = min(128, 2048/(arg2 x block-waves)). (256,4): cap 128 (demand 96,
// spill-free) AND 16 waves/CU as 4 INDEPENDENT blocks -> cross-block pipe overlap.
// LDS 39.4KB/block (single 32KB weight slot, stage-swapped; f16 bias image).
extern "C" __global__ void __launch_bounds__(256, 4)
pinn_main(const float* __restrict__ Sg, const float* __restrict__ Tg,
          const char* __restrict__ ws, float* __restrict__ outg)
{
  extern __shared__ char smem[];     // sS 32K | biasH(f16) 5.6K | Bc+ob 1K
  char* sSw = smem;          const char* sS_ = sSw;
  const f16*   biasH = (const f16*)(smem + 32768);
  const float* BcL   = (const float*)(smem + 38416);

  const int tid  = (int)threadIdx.x;
  const int lane = tid & 63;
  const int wave = tid >> 6;         // 0..3
  const int hi   = lane >> 5;
  const uint32_t lnr   = (uint32_t)(lane & 31);
  const uint32_t hi16v = (uint32_t)hi * 16u;
  const uint32_t SW16  = (lnr & 15u) << 4;
  const int hi4  = hi * 4;

  // this lane's ONE point (2 lanes per point via hi-split of K)
  const int pt = (int)blockIdx.x * 128 + wave * 32 + (int)lnr;
  const int q  = pt < NPTS ? pt : NPTS - 1;
  const float sv = Sg[q], tv = Tg[q];

  // prologue: bias f16 image + Bc/ob (plain vector copies) + inA (async)
  #pragma unroll 1
  for (int o = tid * 16; o < 5648; o += 4096)
    *(f32x4*)(smem + 32768 + o) = *(const f32x4*)(ws + WS_BIAS + o);
  if (tid < 65)
    *(f32x4*)(smem + 38416 + tid * 16) = *(const f32x4*)(ws + WS_BC + tid * 16);
  stage32(ws + WS_INW, sSw, wave, lane);
  __syncthreads();

  f16x8 x0,x1,x2,x3,x4,x5,x6,x7;       // x fragments (32 regs)
  f16x8 u0,u1,u2,u3,u4,u5,u6,u7;       // u fragments (32 regs)

  // ---- input layer: x = sin(30*(ff @ in_w + in_b)); trig once, 4 accs
  {
    f32x16 a0,a1,a2,a3;
    BINIT(a0,0,0) BINIT(a1,0,1) BINIT(a2,0,2) BINIT(a3,0,3)
    FFG(0) FFG(1) FFG(2) FFG(3)
    __syncthreads();                     // inA reads done
    stage32(ws + WS_INW + 32768u, sSw, wave, lane);
    __syncthreads();                     // inB ready
    FFG(4) FFG(5) FFG(6) FFG(7)
    SINPACK(x0,x1,a0) SINPACK(x2,x3,a1) SINPACK(x4,x5,a2) SINPACK(x6,x7,a3)
  }
  __syncthreads();                       // inB reads done
  stage32(ws + WS_W1, sSw, wave, lane);

  // ---- residual blocks
  #pragma unroll 1
  for (int i = 0; i < 8; ++i) {
    const int Mw1 = 1 + 2 * i, Mw2 = 2 + 2 * i;

    __syncthreads();                     // w1_i ready
    W1TILE(0, u0,u1) W1TILE(1, u2,u3) W1TILE(2, u4,u5) W1TILE(3, u6,u7)
    __syncthreads();                     // w1 reads done
    stage32(ws + WS_W2 + (uint32_t)i * 32768u, sSw, wave, lane);
    __syncthreads();                     // w2_i ready
    W2TILE(0, x0,x1) W2TILE(1, x2,x3) W2TILE(2, x4,x5) W2TILE(3, x6,x7)
    __syncthreads();                     // w2 reads done

    if ((i & 1) == 0) {                  // skip from Fourier features
      const int j = i >> 1;
      const int Msk = 17 + j;
      stage32(ws + WS_SKIP + (uint32_t)j * 65536u, sSw, wave, lane);
      f32x16 a0,a1,a2,a3;
      BINIT(a0,Msk,0) BINIT(a1,Msk,1) BINIT(a2,Msk,2) BINIT(a3,Msk,3)
      UNPADD(a0, x0,x1) UNPADD(a1, x2,x3) UNPADD(a2, x4,x5) UNPADD(a3, x6,x7)
      __syncthreads();                   // skipA ready
      FFG(0) FFG(1) FFG(2) FFG(3)
      __syncthreads();                   // skipA reads done
      stage32(ws + WS_SKIP + (uint32_t)j * 65536u + 32768u, sSw, wave, lane);
      __syncthreads();                   // skipB ready
      FFG(4) FFG(5) FFG(6) FFG(7)
      FPACK(x0,x1,a0) FPACK(x2,x3,a1) FPACK(x4,x5,a2) FPACK(x6,x7,a3)
      __syncthreads();                   // skipB reads done
      stage32(ws + WS_W1 + (uint32_t)(i + 1) * 32768u, sSw, wave, lane);
    } else if (i < 7) {
      stage32(ws + WS_W1 + (uint32_t)(i + 1) * 32768u, sSw, wave, lane);
    }
  }

  // ---- output: out = x @ out_w + out_b (2 lanes/pt: fold hi halves)
  float p = 0.0f;
  { const f16* bp = biasH + 21 * 128 + 0 * 32 + hi4; OWDOT(p, x0, x1, bp) }
  { const f16* bp = biasH + 21 * 128 + 1 * 32 + hi4; OWDOT(p, x2, x3, bp) }
  { const f16* bp = biasH + 21 * 128 + 2 * 32 + hi4; OWDOT(p, x4, x5, bp) }
  { const f16* bp = biasH + 21 * 128 + 3 * 32 + hi4; OWDOT(p, x6, x7, bp) }
  p += __shfl_xor(p, 32);
  if (hi == 0 && pt < NPTS) outg[pt] = p + BcL[256];
}

extern "C" void kernel_launch(void* const* d_in, const int* in_sizes, int n_in,
                              void* d_out, int out_size, void* d_ws, size_t ws_size,
                              hipStream_t stream) {
  (void)in_sizes; (void)n_in; (void)out_size;
  const float* S   = (const float*)d_in[0];
  const float* T   = (const float*)d_in[1];
  const float* B   = (const float*)d_in[2];
  const float* inw = (const float*)d_in[3];
  const float* inb = (const float*)d_in[4];
  const float* w1  = (const float*)d_in[5];
  const float* b1  = (const float*)d_in[6];
  const float* w2  = (const float*)d_in[7];
  const float* b2  = (const float*)d_in[8];
  const float* sw  = (const float*)d_in[9];
  const float* sb  = (const float*)d_in[10];
  const float* ow  = (const float*)d_in[11];
  const float* ob  = (const float*)d_in[12];
  char* ws   = (char*)d_ws;
  float* out = (float*)d_out;
  if (ws_size < (size_t)WS_TOTAL) return;

  pinn_prep<<<1677, 256, 0, stream>>>(inw, w1, w2, sw, inb, b1, b2, sb, ow, ob, B, ws);

  const int smem_bytes = 39456;   // 32K slot + 5.6K f16 bias + 1K Bc/ob -> 4 blocks/CU
  hipFuncSetAttribute(reinterpret_cast<const void*>(pinn_main),
                      hipFuncAttributeMaxDynamicSharedMemorySize, smem_bytes);
  const int grid = (NPTS + 127) / 128;   // 3907
  pinn_main<<<grid, 256, smem_bytes, stream>>>(S, T, ws, out);
}

// Round 13
// 604.717 us; speedup vs baseline: 1.1591x; 1.1591x over previous
//
#include <hip/hip_runtime.h>
#include <cstdint>
#include <cstddef>

#define NPTS 500000

using f16   = _Float16;
using f16x4 = __attribute__((ext_vector_type(4))) _Float16;
using f16x8 = __attribute__((ext_vector_type(8))) _Float16;
using f32x4 = __attribute__((ext_vector_type(4))) float;
using f32x16= __attribute__((ext_vector_type(16))) float;

// ---- ws layout (bytes). f16 weight images, pre-transposed W^T[m][k], output rows
// phi-permuted (phi = swap bits 2<->3; double-phi cancels so image k = global k).
// in/skip split into two 32KB halves (groups 0-3 / 4-7, sin/cos K-interleaved).
// Bias image stored f16.
#define WS_INW   0u           // 2 x 32768
#define WS_SKIP  65536u       // 4 x 65536
#define WS_W1    327680u      // 8 x 32768  [128m][128k] f16, pitch 256B
#define WS_W2    589824u      // 8 x 32768  [128m][128k] f16
#define WS_BIAS  851968u      // 22*128 f16: arr[M][pos] = b_M[phi(pos)]
#define WS_BC    863232u      // 256 f32: B coeffs prescaled by 1/(2pi)
#define WS_OB    864256u      // 1 f32 + pad
#define WS_TOTAL 864272u

__device__ __host__ __forceinline__ int phi(int m) {
  return (m & ~12) | ((m & 4) << 1) | ((m & 8) >> 1);
}

// ---------------- prep: pack everything into ws
extern "C" __global__ void pinn_prep(const float* __restrict__ in_w,
                                     const float* __restrict__ w1,
                                     const float* __restrict__ w2,
                                     const float* __restrict__ skw,
                                     const float* __restrict__ inb,
                                     const float* __restrict__ b1,
                                     const float* __restrict__ b2,
                                     const float* __restrict__ skb,
                                     const float* __restrict__ ow,
                                     const float* __restrict__ ob,
                                     const float* __restrict__ Bg,
                                     char* __restrict__ ws) {
  int idx = (int)blockIdx.x * 256 + (int)threadIdx.x;
  if (idx < 32768) {                       // in_w halves [2][128m][128c]
    int H = idx >> 14, r = idx & 16383, m = r >> 7, c = r & 127;
    int gl = c >> 5, sc = (c >> 4) & 1, lo = c & 15;
    int k = sc * 128 + (H * 4 + gl) * 16 + lo;
    uint32_t off = (uint32_t)(m * 256 + c * 2) ^ (uint32_t)((m & 15) << 4);
    *(f16*)(ws + WS_INW + (uint32_t)H * 32768u + off) = (f16)in_w[k * 128 + phi(m)];
  } else if (idx < 163840) {               // skip halves [4][2][128][128]
    int r0 = idx - 32768;
    int j4 = r0 >> 15, rr = r0 & 32767;
    int H = rr >> 14, r = rr & 16383, m = r >> 7, c = r & 127;
    int gl = c >> 5, sc = (c >> 4) & 1, lo = c & 15;
    int k = sc * 128 + (H * 4 + gl) * 16 + lo;
    uint32_t off = (uint32_t)(m * 256 + c * 2) ^ (uint32_t)((m & 15) << 4);
    *(f16*)(ws + WS_SKIP + (uint32_t)j4 * 65536u + (uint32_t)H * 32768u + off) =
        (f16)skw[(j4 * 256 + k) * 128 + phi(m)];
  } else if (idx < 294912) {               // w1 [8][128m][128k]
    int r0 = idx - 163840;
    int i = r0 >> 14, r = r0 & 16383, m = r >> 7, k = r & 127;
    uint32_t off = (uint32_t)(m * 256 + k * 2) ^ (uint32_t)((m & 15) << 4);
    *(f16*)(ws + WS_W1 + (uint32_t)i * 32768u + off) = (f16)w1[(i * 128 + k) * 128 + phi(m)];
  } else if (idx < 425984) {               // w2 [8][128m][128k] f16
    int r0 = idx - 294912;
    int i = r0 >> 14, r = r0 & 16383, m = r >> 7, k = r & 127;
    uint32_t off = (uint32_t)(m * 256 + k * 2) ^ (uint32_t)((m & 15) << 4);
    *(f16*)(ws + WS_W2 + (uint32_t)i * 32768u + off) = (f16)w2[(i * 128 + k) * 128 + phi(m)];
  } else if (idx < 428800) {               // bias image (f16)
    int r = idx - 425984;
    int M = r >> 7, pos = r & 127;
    int pp = phi(pos);
    float v;
    if (M == 0)        v = inb[pp];
    else if (M <= 16)  { int t = M - 1; int i = t >> 1; v = (t & 1) ? b2[i * 128 + pp] : b1[i * 128 + pp]; }
    else if (M <= 20)  v = skb[(M - 17) * 128 + pp];
    else               v = ow[pp];
    *(f16*)(ws + WS_BIAS + (uint32_t)r * 2u) = (f16)v;
  } else if (idx < 429056) {               // Bc coeffs: slot (g,hi): row0 j..j+8, row1 j..j+8
    int r = idx - 428800;
    int slot = r >> 4, e2 = r & 15;
    int kq = slot >> 1, hb = slot & 1;
    int row = e2 >> 3, e = e2 & 7;
    int j = kq * 16 + hb * 8 + e;
    *(float*)(ws + WS_BC + (uint32_t)r * 4u) = Bg[row * 128 + j] * 0.15915494309189535f;
  } else if (idx == 429056) {
    *(float*)(ws + WS_OB) = ob[0];
    *(float*)(ws + WS_OB + 4) = 0.f; *(float*)(ws + WS_OB + 8) = 0.f; *(float*)(ws + WS_OB + 12) = 0.f;
  }
}

// ---------------- device math
__device__ __forceinline__ float ftanh(float x) {
  float e = __builtin_amdgcn_exp2f(x * 2.8853901817f);
  return 1.0f - 2.0f * __builtin_amdgcn_rcpf(e + 1.0f);
}
__device__ __forceinline__ float fsin_rev(float rev) {
  return __builtin_amdgcn_sinf(__builtin_amdgcn_fractf(rev));
}

// async global->LDS, 16B per lane; 2 waves cover 32KB (wave wv: 16KB at wv*16384)
__device__ __forceinline__ void gll16(const char* g, char* l) {
  __builtin_amdgcn_global_load_lds((const __attribute__((address_space(1))) void*)g,
                                   (__attribute__((address_space(3))) void*)l, 16, 0, 0);
}
__device__ __forceinline__ void stage32(const char* g, char* l, int wv, int ln64) {
  const char* gs = g + wv * 16384 + ln64 * 16;
  char* ls = l + wv * 16384;
  #pragma unroll
  for (int it = 0; it < 16; ++it) gll16(gs + it * 1024, ls + it * 1024);
}

#define MFMA_(a,b,c)  __builtin_amdgcn_mfma_f32_32x32x16_f16(a,b,c,0,0,0)

// f16 image fragment load: pitch 256B, XOR mask 15
#define LDW(BASE, MT, KB) (*(const f16x8*)((BASE) + \
  ((((uint32_t)(MT)*32u + lnr)*256u + (uint32_t)(KB)*32u + hi16v) ^ SW16)))

// bias acc init from f16 LDS image (broadcast reads within hi-half)
#define BINIT(acc, Mi, MT) { const f16* _bp = biasH + ((Mi)*128 + (MT)*32 + hi4); \
  f16x4 _q0 = *(const f16x4*)_bp;        f16x4 _q1 = *(const f16x4*)(_bp+8); \
  f16x4 _q2 = *(const f16x4*)(_bp+16);   f16x4 _q3 = *(const f16x4*)(_bp+24); \
  acc[0]=(float)_q0[0]; acc[1]=(float)_q0[1]; acc[2]=(float)_q0[2]; acc[3]=(float)_q0[3]; \
  acc[4]=(float)_q1[0]; acc[5]=(float)_q1[1]; acc[6]=(float)_q1[2]; acc[7]=(float)_q1[3]; \
  acc[8]=(float)_q2[0]; acc[9]=(float)_q2[1]; acc[10]=(float)_q2[2]; acc[11]=(float)_q2[3]; \
  acc[12]=(float)_q3[0]; acc[13]=(float)_q3[1]; acc[14]=(float)_q3[2]; acc[15]=(float)_q3[3]; }

#define UNPADD(acc, F0, F1) { \
  acc[0]+=(float)F0[0]; acc[1]+=(float)F0[1]; acc[2]+=(float)F0[2]; acc[3]+=(float)F0[3]; \
  acc[4]+=(float)F0[4]; acc[5]+=(float)F0[5]; acc[6]+=(float)F0[6]; acc[7]+=(float)F0[7]; \
  acc[8]+=(float)F1[0]; acc[9]+=(float)F1[1]; acc[10]+=(float)F1[2]; acc[11]+=(float)F1[3]; \
  acc[12]+=(float)F1[4]; acc[13]+=(float)F1[5]; acc[14]+=(float)F1[6]; acc[15]+=(float)F1[7]; }

#define FPACK(F0, F1, acc) { f16x8 _g0, _g1; \
  _g0[0]=(f16)acc[0]; _g0[1]=(f16)acc[1]; _g0[2]=(f16)acc[2]; _g0[3]=(f16)acc[3]; \
  _g0[4]=(f16)acc[4]; _g0[5]=(f16)acc[5]; _g0[6]=(f16)acc[6]; _g0[7]=(f16)acc[7]; \
  _g1[0]=(f16)acc[8]; _g1[1]=(f16)acc[9]; _g1[2]=(f16)acc[10]; _g1[3]=(f16)acc[11]; \
  _g1[4]=(f16)acc[12]; _g1[5]=(f16)acc[13]; _g1[6]=(f16)acc[14]; _g1[7]=(f16)acc[15]; \
  F0=_g0; F1=_g1; }

#define TPACK(F0, F1, acc) { f16x8 _g0, _g1; \
  _g0[0]=(f16)ftanh(acc[0]); _g0[1]=(f16)ftanh(acc[1]); _g0[2]=(f16)ftanh(acc[2]); _g0[3]=(f16)ftanh(acc[3]); \
  _g0[4]=(f16)ftanh(acc[4]); _g0[5]=(f16)ftanh(acc[5]); _g0[6]=(f16)ftanh(acc[6]); _g0[7]=(f16)ftanh(acc[7]); \
  _g1[0]=(f16)ftanh(acc[8]); _g1[1]=(f16)ftanh(acc[9]); _g1[2]=(f16)ftanh(acc[10]); _g1[3]=(f16)ftanh(acc[11]); \
  _g1[4]=(f16)ftanh(acc[12]); _g1[5]=(f16)ftanh(acc[13]); _g1[6]=(f16)ftanh(acc[14]); _g1[7]=(f16)ftanh(acc[15]); \
  F0=_g0; F1=_g1; }

#define OM2PI 4.7746482927f
#define SINPACK(F0, F1, acc) { f16x8 _g0, _g1; \
  _g0[0]=(f16)fsin_rev(acc[0]*OM2PI); _g0[1]=(f16)fsin_rev(acc[1]*OM2PI); \
  _g0[2]=(f16)fsin_rev(acc[2]*OM2PI); _g0[3]=(f16)fsin_rev(acc[3]*OM2PI); \
  _g0[4]=(f16)fsin_rev(acc[4]*OM2PI); _g0[5]=(f16)fsin_rev(acc[5]*OM2PI); \
  _g0[6]=(f16)fsin_rev(acc[6]*OM2PI); _g0[7]=(f16)fsin_rev(acc[7]*OM2PI); \
  _g1[0]=(f16)fsin_rev(acc[8]*OM2PI); _g1[1]=(f16)fsin_rev(acc[9]*OM2PI); \
  _g1[2]=(f16)fsin_rev(acc[10]*OM2PI); _g1[3]=(f16)fsin_rev(acc[11]*OM2PI); \
  _g1[4]=(f16)fsin_rev(acc[12]*OM2PI); _g1[5]=(f16)fsin_rev(acc[13]*OM2PI); \
  _g1[6]=(f16)fsin_rev(acc[14]*OM2PI); _g1[7]=(f16)fsin_rev(acc[15]*OM2PI); \
  F0=_g0; F1=_g1; }

// trig for feature slot ei of this lane's ONE point (sv,tv)
#define FFE(ei, CA, CB) { \
  float _r = __builtin_amdgcn_fractf(sv*(CA) + tv*(CB)); \
  _s[ei] = (f16)__builtin_amdgcn_sinf(_r); _c[ei] = (f16)__builtin_amdgcn_cosf(_r); }
#define FF2(G, FS, FC) { const float* _cp = BcL + ((G)*2 + hi)*16; \
  f32x4 _a0 = *(const f32x4*)_cp, _a1 = *(const f32x4*)(_cp+4); \
  f32x4 _b0 = *(const f32x4*)(_cp+8), _b1 = *(const f32x4*)(_cp+12); \
  f16x8 _s, _c; \
  FFE(0,_a0[0],_b0[0]) FFE(1,_a0[1],_b0[1]) FFE(2,_a0[2],_b0[2]) FFE(3,_a0[3],_b0[3]) \
  FFE(4,_a1[0],_b1[0]) FFE(5,_a1[1],_b1[1]) FFE(6,_a1[2],_b1[2]) FFE(7,_a1[3],_b1[7-4]) \
  FS = _s; FC = _c; }

// one Fourier group into all 4 mtile accs (trig computed ONCE per layer per g)
#define FFG(G) { f16x8 _fs,_fc; FF2(G,_fs,_fc) \
  { f16x8 _w=LDW(sS_,0,((G)&3)*2);   a0=MFMA_(_w,_fs,a0); } \
  { f16x8 _w=LDW(sS_,0,((G)&3)*2+1); a0=MFMA_(_w,_fc,a0); } \
  { f16x8 _w=LDW(sS_,1,((G)&3)*2);   a1=MFMA_(_w,_fs,a1); } \
  { f16x8 _w=LDW(sS_,1,((G)&3)*2+1); a1=MFMA_(_w,_fc,a1); } \
  { f16x8 _w=LDW(sS_,2,((G)&3)*2);   a2=MFMA_(_w,_fs,a2); } \
  { f16x8 _w=LDW(sS_,2,((G)&3)*2+1); a2=MFMA_(_w,_fc,a2); } \
  { f16x8 _w=LDW(sS_,3,((G)&3)*2);   a3=MFMA_(_w,_fs,a3); } \
  { f16x8 _w=LDW(sS_,3,((G)&3)*2+1); a3=MFMA_(_w,_fc,a3); } }

#define W1K(kb) { f16x8 _a = LDW(sS_, MTv, kb); acc = MFMA_(_a, x##kb, acc); }
#define W1TILE(MT, U0, U1) { const uint32_t MTv = (MT); \
  f32x16 acc; BINIT(acc, Mw1, MT) \
  W1K(0) W1K(1) W1K(2) W1K(3) W1K(4) W1K(5) W1K(6) W1K(7) \
  TPACK(U0, U1, acc) }

#define W2K(kb) { f16x8 _a = LDW(sS_, MTv, kb); acc = MFMA_(_a, u##kb, acc); }
#define W2TILE(MT, X0, X1) { const uint32_t MTv = (MT); \
  f32x16 acc; BINIT(acc, Mw2, MT) \
  W2K(0) W2K(1) W2K(2) W2K(3) W2K(4) W2K(5) W2K(6) W2K(7) \
  f16x8 _t0,_t1; FPACK(_t0,_t1,acc) X0 = X0 + _t0; X1 = X1 + _t1; }   // v_pk_add_f16

#define OWDOT(P, F0, F1, bp) P += (float)F0[0]*(float)bp[0] + (float)F0[1]*(float)bp[1] \
  + (float)F0[2]*(float)bp[2]  + (float)F0[3]*(float)bp[3] \
  + (float)F0[4]*(float)bp[8]  + (float)F0[5]*(float)bp[9] \
  + (float)F0[6]*(float)bp[10] + (float)F0[7]*(float)bp[11] \
  + (float)F1[0]*(float)bp[16] + (float)F1[1]*(float)bp[17] \
  + (float)F1[2]*(float)bp[18] + (float)F1[3]*(float)bp[19] \
  + (float)F1[4]*(float)bp[24] + (float)F1[5]*(float)bp[25] \
  + (float)F1[6]*(float)bp[26] + (float)F1[7]*(float)bp[27];

// ---------------- main: 128 thr = 2 waves x 32 pts = 64 pts/block; 4 blocks/CU.
// Measured toolchain law (R2..R12): VGPR cap = min(128, 256/arg2); arg2 caps
// residency at arg2 waves/EU. (128,2): cap 128 (demand ~96, spill-free — R11) AND
// 4 independent blocks/CU (LDS 39.4KB x4) -> cross-block barrier-domain overlap
// (mechanism proven in R12 at 43% occ). Same 8 waves/CU as R11, 4 phase domains.
extern "C" __global__ void __launch_bounds__(128, 2)
pinn_main(const float* __restrict__ Sg, const float* __restrict__ Tg,
          const char* __restrict__ ws, float* __restrict__ outg)
{
  extern __shared__ char smem[];     // sS 32K | biasH(f16) 5.6K | Bc+ob 1K
  char* sSw = smem;          const char* sS_ = sSw;
  const f16*   biasH = (const f16*)(smem + 32768);
  const float* BcL   = (const float*)(smem + 38416);

  const int tid  = (int)threadIdx.x;
  const int lane = tid & 63;
  const int wave = tid >> 6;         // 0..1
  const int hi   = lane >> 5;
  const uint32_t lnr   = (uint32_t)(lane & 31);
  const uint32_t hi16v = (uint32_t)hi * 16u;
  const uint32_t SW16  = (lnr & 15u) << 4;
  const int hi4  = hi * 4;

  // this lane's ONE point (2 lanes per point via hi-split of K)
  const int pt = (int)blockIdx.x * 64 + wave * 32 + (int)lnr;
  const int q  = pt < NPTS ? pt : NPTS - 1;
  const float sv = Sg[q], tv = Tg[q];

  // prologue: bias f16 image + Bc/ob (plain vector copies) + inA (async)
  #pragma unroll 1
  for (int o = tid * 16; o < 5648; o += 2048)
    *(f32x4*)(smem + 32768 + o) = *(const f32x4*)(ws + WS_BIAS + o);
  if (tid < 65)
    *(f32x4*)(smem + 38416 + tid * 16) = *(const f32x4*)(ws + WS_BC + tid * 16);
  stage32(ws + WS_INW, sSw, wave, lane);
  __syncthreads();

  f16x8 x0,x1,x2,x3,x4,x5,x6,x7;       // x fragments (32 regs)
  f16x8 u0,u1,u2,u3,u4,u5,u6,u7;       // u fragments (32 regs)

  // ---- input layer: x = sin(30*(ff @ in_w + in_b)); trig once, 4 accs
  {
    f32x16 a0,a1,a2,a3;
    BINIT(a0,0,0) BINIT(a1,0,1) BINIT(a2,0,2) BINIT(a3,0,3)
    FFG(0) FFG(1) FFG(2) FFG(3)
    __syncthreads();                     // inA reads done
    stage32(ws + WS_INW + 32768u, sSw, wave, lane);
    __syncthreads();                     // inB ready
    FFG(4) FFG(5) FFG(6) FFG(7)
    SINPACK(x0,x1,a0) SINPACK(x2,x3,a1) SINPACK(x4,x5,a2) SINPACK(x6,x7,a3)
  }
  __syncthreads();                       // inB reads done
  stage32(ws + WS_W1, sSw, wave, lane);

  // ---- residual blocks
  #pragma unroll 1
  for (int i = 0; i < 8; ++i) {
    const int Mw1 = 1 + 2 * i, Mw2 = 2 + 2 * i;

    __syncthreads();                     // w1_i ready
    W1TILE(0, u0,u1) W1TILE(1, u2,u3) W1TILE(2, u4,u5) W1TILE(3, u6,u7)
    __syncthreads();                     // w1 reads done
    stage32(ws + WS_W2 + (uint32_t)i * 32768u, sSw, wave, lane);
    __syncthreads();                     // w2_i ready
    W2TILE(0, x0,x1) W2TILE(1, x2,x3) W2TILE(2, x4,x5) W2TILE(3, x6,x7)
    __syncthreads();                     // w2 reads done

    if ((i & 1) == 0) {                  // skip from Fourier features
      const int j = i >> 1;
      const int Msk = 17 + j;
      stage32(ws + WS_SKIP + (uint32_t)j * 65536u, sSw, wave, lane);
      f32x16 a0,a1,a2,a3;
      BINIT(a0,Msk,0) BINIT(a1,Msk,1) BINIT(a2,Msk,2) BINIT(a3,Msk,3)
      UNPADD(a0, x0,x1) UNPADD(a1, x2,x3) UNPADD(a2, x4,x5) UNPADD(a3, x6,x7)
      __syncthreads();                   // skipA ready
      FFG(0) FFG(1) FFG(2) FFG(3)
      __syncthreads();                   // skipA reads done
      stage32(ws + WS_SKIP + (uint32_t)j * 65536u + 32768u, sSw, wave, lane);
      __syncthreads();                   // skipB ready
      FFG(4) FFG(5) FFG(6) FFG(7)
      FPACK(x0,x1,a0) FPACK(x2,x3,a1) FPACK(x4,x5,a2) FPACK(x6,x7,a3)
      __syncthreads();                   // skipB reads done
      stage32(ws + WS_W1 + (uint32_t)(i + 1) * 32768u, sSw, wave, lane);
    } else if (i < 7) {
      stage32(ws + WS_W1 + (uint32_t)(i + 1) * 32768u, sSw, wave, lane);
    }
  }

  // ---- output: out = x @ out_w + out_b (2 lanes/pt: fold hi halves)
  float p = 0.0f;
  { const f16* bp = biasH + 21 * 128 + 0 * 32 + hi4; OWDOT(p, x0, x1, bp) }
  { const f16* bp = biasH + 21 * 128 + 1 * 32 + hi4; OWDOT(p, x2, x3, bp) }
  { const f16* bp = biasH + 21 * 128 + 2 * 32 + hi4; OWDOT(p, x4, x5, bp) }
  { const f16* bp = biasH + 21 * 128 + 3 * 32 + hi4; OWDOT(p, x6, x7, bp) }
  p += __shfl_xor(p, 32);
  if (hi == 0 && pt < NPTS) outg[pt] = p + BcL[256];
}

extern "C" void kernel_launch(void* const* d_in, const int* in_sizes, int n_in,
                              void* d_out, int out_size, void* d_ws, size_t ws_size,
                              hipStream_t stream) {
  (void)in_sizes; (void)n_in; (void)out_size;
  const float* S   = (const float*)d_in[0];
  const float* T   = (const float*)d_in[1];
  const float* B   = (const float*)d_in[2];
  const float* inw = (const float*)d_in[3];
  const float* inb = (const float*)d_in[4];
  const float* w1  = (const float*)d_in[5];
  const float* b1  = (const float*)d_in[6];
  const float* w2  = (const float*)d_in[7];
  const float* b2  = (const float*)d_in[8];
  const float* sw  = (const float*)d_in[9];
  const float* sb  = (const float*)d_in[10];
  const float* ow  = (const float*)d_in[11];
  const float* ob  = (const float*)d_in[12];
  char* ws   = (char*)d_ws;
  float* out = (float*)d_out;
  if (ws_size < (size_t)WS_TOTAL) return;

  pinn_prep<<<1677, 256, 0, stream>>>(inw, w1, w2, sw, inb, b1, b2, sb, ow, ob, B, ws);

  const int smem_bytes = 39456;   // 32K slot + 5.6K f16 bias + 1K Bc/ob -> 4 blocks/CU
  hipFuncSetAttribute(reinterpret_cast<const void*>(pinn_main),
                      hipFuncAttributeMaxDynamicSharedMemorySize, smem_bytes);
  const int grid = (NPTS + 63) / 64;   // 7813
  pinn_main<<<grid, 128, smem_bytes, stream>>>(S, T, ws, out);
}